// Round 5
// baseline (10.597 us; speedup 1.0000x reference)
//
#include <hip/hip_runtime.h>
#include <hip/hip_bf16.h>

// Gather: out[b, s, :] = hidden_states[b, pos[b, s], :]
// B=32, SEQ=4096, SENT=128, DIM=512, fp32.
//
// R4 (10.40 us): 512 WG x 1024 thr, 1 float4/thread. WG-count cut 2048->512
// gave -1.5 us => dispatch ramp is a real term.
// R5 A/B: 256 WG x 1024 thr, 2 float4/thread (stride TOTAL/2). One block per
// CU, 16 waves/CU, both gather chains issued back-to-back (MLP=2). Same
// coalescing, same cached stores.

#define BATCH 32
#define SEQ   4096
#define SENT  128
#define DIM   512
#define DIM4  (DIM / 4)        // 128 float4 per row
#define TOTAL4 (BATCH * SENT * DIM4)   // 524288
#define HALF4  (TOTAL4 / 2)            // 262144

__global__ __launch_bounds__(1024) void gather_rows_kernel(
    const float4* __restrict__ hs,   // (B, SEQ, DIM/4)
    const int*    __restrict__ pos,  // (B, SENT)
    float4*       __restrict__ out)  // (B, SENT, DIM/4)
{
    const int t0 = blockIdx.x * blockDim.x + threadIdx.x;  // [0, 262144)
    const int t1 = t0 + HALF4;

    // Chain 0
    const int d0   = t0 & (DIM4 - 1);
    const int row0 = t0 >> 7;
    const int b0   = row0 >> 7;
    // Chain 1
    const int d1   = t1 & (DIM4 - 1);
    const int row1 = t1 >> 7;
    const int b1   = row1 >> 7;

    const int p0 = pos[row0];
    const int p1 = pos[row1];

    float4 v0 = hs[((size_t)b0 * SEQ + p0) * DIM4 + d0];
    float4 v1 = hs[((size_t)b1 * SEQ + p1) * DIM4 + d1];

    out[t0] = v0;
    out[t1] = v1;
}

extern "C" void kernel_launch(void* const* d_in, const int* in_sizes, int n_in,
                              void* d_out, int out_size, void* d_ws, size_t ws_size,
                              hipStream_t stream) {
    const float4* hs  = (const float4*)d_in[0];
    const int*    pos = (const int*)d_in[1];
    float4*       out = (float4*)d_out;

    gather_rows_kernel<<<HALF4 / 1024, 1024, 0, stream>>>(hs, pos, out);  // 256 WG
}

// Round 6
// 10.429 us; speedup vs baseline: 1.0161x; 1.0161x over previous
//
#include <hip/hip_runtime.h>
#include <hip/hip_bf16.h>

// Gather: out[b, s, :] = hidden_states[b, pos[b, s], :]
// B=32, SEQ=4096, SENT=128, DIM=512, fp32.
//
// R4 (10.40 us, best): 512 WG x 1024 thr, 1 float4/thread, cached stores.
// R6 A/B: ONLY change = scalarize the pos fetch. row = tid>>7 is wave-uniform
// (64-aligned 64-tid spans never straddle a 128-boundary), so readfirstlane
// lets the compiler emit one s_load per wave instead of 64 per-lane vector
// loads, shortening the pos->gather dependency chain.

#define BATCH 32
#define SEQ   4096
#define SENT  128
#define DIM   512
#define DIM4  (DIM / 4)   // 128 float4 per row

__global__ __launch_bounds__(1024) void gather_rows_kernel(
    const float4* __restrict__ hs,   // (B, SEQ, DIM/4)
    const int*    __restrict__ pos,  // (B, SENT)
    float4*       __restrict__ out)  // (B, SENT, DIM/4)
{
    const int tid = blockIdx.x * blockDim.x + threadIdx.x;  // [0, 524288)
    const int d   = tid & (DIM4 - 1);                       // per-lane
    const int row = __builtin_amdgcn_readfirstlane(tid >> 7); // wave-uniform
    const int b   = row >> 7;                               // SENT = 128 = 2^7
    const int p   = pos[row];                               // scalar s_load

    out[tid] = hs[((size_t)b * SEQ + p) * DIM4 + d];
}

extern "C" void kernel_launch(void* const* d_in, const int* in_sizes, int n_in,
                              void* d_out, int out_size, void* d_ws, size_t ws_size,
                              hipStream_t stream) {
    const float4* hs  = (const float4*)d_in[0];
    const int*    pos = (const int*)d_in[1];
    float4*       out = (float4*)d_out;

    const int total4 = BATCH * SENT * DIM4;     // 524288
    gather_rows_kernel<<<total4 / 1024, 1024, 0, stream>>>(hs, pos, out);
}